// Round 13
// baseline (189.039 us; speedup 1.0000x reference)
//
#include <hip/hip_runtime.h>
#include <stdint.h>

typedef unsigned int u32;
typedef unsigned long long u64;

#define N_BOXES 6291456   // 128*128*128*3
#define N_FLOAT4 7864320  // N_BOXES*5/4  = 2048*256*15 exactly
#define KCAND 4096
#define TOPK 300
#define CAP 16384         // compact capacity; ~8.5K expected at s>=3.0 for this data
#define SCORE_TH -3.0f
#define NMS_TH 0.05f
#define FIXED_TH 3.0f     // conservative compact threshold (bin 0xC04)

__device__ __forceinline__ u32 sortable(float f) {
    u32 b = __float_as_uint(f);
    return (b & 0x80000000u) ? ~b : (b | 0x80000000u);
}

// Extract the (at most one) score in float4 #g: element index 4g+k with
// (4g+k) % 5 == 0. Returns false iff (4g)%5 == 1 (no score in this quad).
__device__ __forceinline__ bool quad_score(const float4& v, u32 g, float& s, u32& bidx) {
    u32 r = (4u * g) % 5u;
    if (r == 1u) return false;
    u32 k = (r == 0u) ? 0u : (5u - r);          // 0,3,2,1 for r=0,2,3,4
    s = (k == 0u) ? v.x : ((k == 1u) ? v.y : ((k == 2u) ? v.z : v.w));
    bidx = (4u * g + k) / 5u;
    return true;
}

// ---- Pass 1: compact all scores >= FIXED_TH (hot loop = loads+VALU only) ----
__global__ __launch_bounds__(256) void k_scan(const float4* __restrict__ in4,
                                              u32* __restrict__ cnt,
                                              u32* __restrict__ ckey, u32* __restrict__ cidx) {
    u32 base = blockIdx.x * 256u + threadIdx.x;
    u32 hits = 0;
#pragma unroll
    for (int k = 0; k < 15; ++k) {
        u32 g = base + (u32)k * 524288u;
        float4 v = in4[g];
        float s; u32 bidx;
        if (quad_score(v, g, s, bidx) && s >= FIXED_TH) hits |= 1u << k;
    }
    // rare path: re-read hit quads (L1/L2-hot), compact exactly once each
    while (hits) {
        int k = __builtin_ctz(hits);
        hits &= hits - 1;
        u32 g = base + (u32)k * 524288u;
        float4 v = in4[g];
        float s; u32 bidx;
        if (quad_score(v, g, s, bidx)) {
            u32 pos = atomicAdd(&cnt[0], 1u);
            if (pos < (u32)CAP) { ckey[pos] = sortable(s); cidx[pos] = bidx; }
        }
    }
}

// ---- Pass 2: validate the conservative compact; arm fallback if needed ----
__global__ void k_check(u32* __restrict__ cnt) {
    u32 m = cnt[0];
    u32 ok = (m >= (u32)KCAND && m <= (u32)CAP) ? 1u : 0u;
    cnt[2] = ok;
    if (!ok) cnt[0] = 0;   // fallback refills from scratch with exact B*
}

// ---- Fallback chain (guarded; no-ops when cnt[2]==1, the common case) ----
__global__ void k_hist_fb(const float* __restrict__ in, const u32* __restrict__ cnt,
                          u32* __restrict__ hist) {
    if (cnt[2] == 1u) return;
    __shared__ u32 lh[4096];
    for (int k = threadIdx.x; k < 4096; k += blockDim.x) lh[k] = 0;
    __syncthreads();
    int stride = gridDim.x * blockDim.x;
    for (int i = blockIdx.x * blockDim.x + threadIdx.x; i < N_BOXES; i += stride) {
        float f = in[(size_t)i * 5];
        u32 key = (f > SCORE_TH) ? sortable(f) : 0u;
        atomicAdd(&lh[key >> 20], 1u);
    }
    __syncthreads();
    for (int k = threadIdx.x; k < 4096; k += blockDim.x)
        if (lh[k]) atomicAdd(&hist[k], lh[k]);
}

__global__ void k_pivot_fb(const u32* __restrict__ hist, u32* __restrict__ cnt) {
    if (cnt[2] == 1u) return;
    __shared__ u32 part[256];
    int t = threadIdx.x;
    u32 s = 0;
    for (int k = 0; k < 16; ++k) s += hist[t * 16 + k];
    part[t] = s;
    __syncthreads();
    if (t == 0) {
        u32 acc = 0; int chunk = -1;
        for (int c = 255; c >= 0; --c) {
            if (acc + part[c] >= (u32)KCAND) { chunk = c; break; }
            acc += part[c];
        }
        u32 bstar = 0;
        if (chunk >= 0) {
            for (int b = chunk * 16 + 15; b >= chunk * 16; --b) {
                acc += hist[b];
                if (acc >= (u32)KCAND) { bstar = (u32)b; break; }
            }
        }
        cnt[1] = bstar;
    }
}

__global__ void k_compact_fb(const float* __restrict__ in, u32* __restrict__ cnt,
                             u32* __restrict__ ckey, u32* __restrict__ cidx) {
    if (cnt[2] == 1u) return;
    u32 bstar = cnt[1];
    int stride = gridDim.x * blockDim.x;
    for (int i = blockIdx.x * blockDim.x + threadIdx.x; i < N_BOXES; i += stride) {
        float f = in[(size_t)i * 5];
        u32 key = (f > SCORE_TH) ? sortable(f) : 0u;
        if ((key >> 20) >= bstar) {
            u32 pos = atomicAdd(&cnt[0], 1u);
            if (pos < (u32)CAP) { ckey[pos] = key; cidx[pos] = (u32)i; }
        }
    }
}

// ---- Pass 4: exact rank by (key desc, idx asc); grid (CAP/256, CAP/1024) ----
__global__ void k_rank(const u32* __restrict__ ckey, const u32* __restrict__ cidx,
                       const u32* __restrict__ cnt, u32* __restrict__ rank) {
    int M = (int)min(cnt[0], (u32)CAP);
    int e = blockIdx.x * 256 + threadIdx.x;
    bool act = (e < M);
    u32 mykey = 0, myidx = 0;
    if (act) { mykey = ckey[e]; myidx = cidx[e]; }
    int j0 = blockIdx.y * 1024;
    int j1 = min(j0 + 1024, M);
    __shared__ u32 sk[256], si[256];
    u32 r = 0;
    for (int base = j0; base < j1; base += 256) {
        __syncthreads();
        int jj = base + threadIdx.x;
        if (jj < j1) { sk[threadIdx.x] = ckey[jj]; si[threadIdx.x] = cidx[jj]; }
        __syncthreads();
        int lim = min(256, j1 - base);
        if (act) {
            for (int q = 0; q < lim; ++q) {
                u32 kq = sk[q];
                r += (u32)((kq > mykey) || (kq == mykey && si[q] < myidx));
            }
        }
    }
    if (act && r) atomicAdd(&rank[e], r);
}

__global__ void k_scatter(const u32* __restrict__ ckey, const u32* __restrict__ cidx,
                          const u32* __restrict__ cnt, const u32* __restrict__ rank,
                          u32* __restrict__ skey, u32* __restrict__ sidx) {
    int M = (int)min(cnt[0], (u32)CAP);
    int e = blockIdx.x * 256 + threadIdx.x;
    if (e < M) {
        u32 r = rank[e];
        if (r < (u32)KCAND) { skey[r] = ckey[e]; sidx[r] = cidx[e]; }
    }
}

// ---- Pass 5: decode the 4096 selected boxes; build validity bitmask ----
__global__ void k_decode(const float* __restrict__ in, const u32* __restrict__ skey,
                         const u32* __restrict__ sidx, float* __restrict__ cand,
                         u64* __restrict__ keepg) {
#pragma clang fp contract(off)
    int r = blockIdx.x * 256 + threadIdx.x;   // grid 16 x 256 = 4096 exactly
    u32 key = skey[r];
    u32 idx = sidx[r];
    u32 a = idx % 3u;
    u32 rem = idx / 3u;
    u32 w = rem & 127u; rem >>= 7;
    u32 h = rem & 127u;
    u32 z = rem >> 7;
    float anch = (a == 0u) ? 10.0f : ((a == 1u) ? 30.0f : 60.0f);
    const float* p = in + (size_t)idx * 5;
    float s  = p[0];
    float zc = (1.5f + 4.0f * (float)z) + p[1] * anch;
    float yc = (1.5f + 4.0f * (float)h) + p[2] * anch;
    float xc = (1.5f + 4.0f * (float)w) + p[3] * anch;
    float d  = expf(p[4]) * anch;
    float* o = cand + (size_t)r * 5;
    o[0] = s; o[1] = zc; o[2] = yc; o[3] = xc; o[4] = d;
    u64 bal = __ballot(key != 0u);    // valid = score > THRESH (key==0 means filtered)
    if ((threadIdx.x & 63) == 0) keepg[r >> 6] = bal;
}

// ---- Pass 6: 4096x4096 suppression bitmask + contiguous diag-plane ----
// dp[i] = mask[i][i>>6]  (the word holding row i's intra-chunk bits)
__global__ void k_mask(const float* __restrict__ cand, u64* __restrict__ mask,
                       u64* __restrict__ dp) {
#pragma clang fp contract(off)
    int i = blockIdx.y;
    int wv = blockIdx.x * 4 + (threadIdx.x >> 6);
    int j = wv * 64 + (threadIdx.x & 63);
    const float* bi = cand + (size_t)i * 5;
    const float* bj = cand + (size_t)j * 5;
    float zi = bi[1], yi = bi[2], xi = bi[3], di = bi[4];
    float zj = bj[1], yj = bj[2], xj = bj[3], dj = bj[4];
    float ri = di * 0.5f, rj = dj * 0.5f;
    float ov0 = fmaxf(0.0f, fminf(zi + ri, zj + rj) - fmaxf(zi - ri, zj - rj));
    float ov1 = fmaxf(0.0f, fminf(yi + ri, yj + rj) - fmaxf(yi - ri, yj - rj));
    float ov2 = fmaxf(0.0f, fminf(xi + ri, xj + rj) - fmaxf(xi - ri, xj - rj));
    float inter = (ov0 * ov1) * ov2;
    float vi = (di * di) * di;
    float vj = (dj * dj) * dj;
    float iou = inter / ((vi + vj) - inter);
    bool bit = (j > i) && (iou >= NMS_TH);
    u64 bal = __ballot(bit);
    if ((threadIdx.x & 63) == 0) {
        mask[(size_t)i * 64 + wv] = bal;
        if (wv == (i >> 6)) dp[i] = bal;
    }
}

// ---- Pass 7: greedy NMS — single wave, diag-plane resolve + kept-row apply.
// Lane l holds keep word l. Per chunk we read ONLY the 512B diag slice and
// the ~kept rows (512B each, coalesced) instead of the full 32KB chunk.
// Rows carry only j>i bits, so the one-shot OR reproduces greedy exactly
// (word c included). Early exit once TOPK boxes are kept.
__global__ __launch_bounds__(64) void k_nms(const u64* __restrict__ mask,
                                            const u64* __restrict__ dp,
                                            u64* __restrict__ keepg,
                                            u32* __restrict__ cnt) {
    int lane = threadIdx.x;
    u64 K = keepg[lane];
    int keptTotal = 0;
    int resolved = 63;
    u64 dcur = dp[lane];                       // chunk 0 diag plane
    for (int c = 0; c < 64; ++c) {
        u64 dnext = (c + 1 < 64) ? dp[(c + 1) * 64 + lane] : 0ull;  // prefetch
        // resolve: scalar greedy over surviving bits of keep word c
        u32 dlo = (u32)dcur, dhi = (u32)(dcur >> 32);
        u32 kwlo = (u32)__builtin_amdgcn_readlane((int)(u32)K, c);
        u32 kwhi = (u32)__builtin_amdgcn_readlane((int)(u32)(K >> 32), c);
        u64 remaining = ((u64)kwhi << 32) | kwlo;
        u64 kept = 0;
        while (remaining) {
            int b = __builtin_ctzll(remaining);
            kept |= 1ull << b;
            u32 rlo = (u32)__builtin_amdgcn_readlane((int)dlo, b);
            u32 rhi = (u32)__builtin_amdgcn_readlane((int)dhi, b);
            u64 rb = ((u64)rhi << 32) | rlo;   // bits > b only
            remaining &= ~(rb | (1ull << b));
        }
        // apply: wave-load each kept row (lane l reads word l), 8-wide groups
        const u64* rows = mask + (size_t)c * 4096;   // row base for chunk c
        u64 sup = 0;
        u64 kk = kept;
        while (kk) {
            int b0 = __builtin_ctzll(kk); kk &= kk - 1;
            int b1 = -1, b2 = -1, b3 = -1, b4 = -1, b5 = -1, b6 = -1, b7 = -1;
            if (kk) { b1 = __builtin_ctzll(kk); kk &= kk - 1; }
            if (kk) { b2 = __builtin_ctzll(kk); kk &= kk - 1; }
            if (kk) { b3 = __builtin_ctzll(kk); kk &= kk - 1; }
            if (kk) { b4 = __builtin_ctzll(kk); kk &= kk - 1; }
            if (kk) { b5 = __builtin_ctzll(kk); kk &= kk - 1; }
            if (kk) { b6 = __builtin_ctzll(kk); kk &= kk - 1; }
            if (kk) { b7 = __builtin_ctzll(kk); kk &= kk - 1; }
            u64 v0 = rows[(size_t)b0 * 64 + lane];
            u64 v1 = (b1 >= 0) ? rows[(size_t)b1 * 64 + lane] : 0ull;
            u64 v2 = (b2 >= 0) ? rows[(size_t)b2 * 64 + lane] : 0ull;
            u64 v3 = (b3 >= 0) ? rows[(size_t)b3 * 64 + lane] : 0ull;
            u64 v4 = (b4 >= 0) ? rows[(size_t)b4 * 64 + lane] : 0ull;
            u64 v5 = (b5 >= 0) ? rows[(size_t)b5 * 64 + lane] : 0ull;
            u64 v6 = (b6 >= 0) ? rows[(size_t)b6 * 64 + lane] : 0ull;
            u64 v7 = (b7 >= 0) ? rows[(size_t)b7 * 64 + lane] : 0ull;
            sup |= ((v0 | v1) | (v2 | v3)) | ((v4 | v5) | (v6 | v7));
        }
        K &= ~sup;
        keptTotal += (int)__popcll(kept);
        if (keptTotal >= TOPK) { resolved = c; break; }
        dcur = dnext;
    }
    keepg[lane] = K;
    if (lane == 0) cnt[3] = (u32)resolved;     // last word with final keep bits
}

// ---- Pass 8: final top-300 = kept positions asc, then non-kept asc ----
__global__ void k_final(const float* __restrict__ cand, const u64* __restrict__ keepg,
                        const u32* __restrict__ cnt, float* __restrict__ outp) {
    __shared__ u64 kw[64];
    __shared__ u32 wp[65];
    int t = threadIdx.x;   // 256
    int limit = (int)cnt[3];
    if (t < 64) kw[t] = (t <= limit) ? keepg[t] : 0ull;
    __syncthreads();
    if (t == 0) {
        u32 acc = 0;
        for (int wv = 0; wv < 64; ++wv) { wp[wv] = acc; acc += (u32)__popcll(kw[wv]); }
        wp[64] = acc;
    }
    __syncthreads();
    u32 nk = wp[64];
    int rmax = (limit + 1) * 64;
    for (int r = t; r < rmax; r += 256) {
        u64 word = kw[r >> 6];
        int b = r & 63;
        bool kept = (word >> b) & 1ull;
        u64 lowmask = b ? (~0ull >> (64 - b)) : 0ull;
        u32 before = wp[r >> 6] + (u32)__popcll(word & lowmask);
        u32 slot = kept ? before : (nk + (u32)r - before);
        if (slot < (u32)TOPK) {
            const float* src = cand + (size_t)r * 5;
            float* dst = outp + (size_t)slot * 5;
            dst[0] = src[0]; dst[1] = src[1]; dst[2] = src[2];
            dst[3] = src[3]; dst[4] = src[4];
        }
    }
}

extern "C" void kernel_launch(void* const* d_in, const int* in_sizes, int n_in,
                              void* d_out, int out_size, void* d_ws, size_t ws_size,
                              hipStream_t stream) {
    const float* in = (const float*)d_in[0];
    const float4* in4 = (const float4*)d_in[0];
    float* outp = (float*)d_out;
    char* ws = (char*)d_ws;

    // workspace layout (bytes), CAP = 16384
    u32* hist = (u32*)(ws + 0);            // 16384
    u32* cnt  = (u32*)(ws + 16384);        // 64
    u32* rank = (u32*)(ws + 16448);        // 65536
    u32* ckey = (u32*)(ws + 81984);        // 65536
    u32* cidx = (u32*)(ws + 147520);       // 65536
    u32* skey = (u32*)(ws + 213056);       // 16384
    u32* sidx = (u32*)(ws + 229440);       // 16384
    float* cand = (float*)(ws + 245824);   // 81920
    u64* keepg  = (u64*)(ws + 327744);     // 512
    u64* mask   = (u64*)(ws + 328256);     // 2097152
    u64* dp     = (u64*)(ws + 2425408);    // 32768     (total ~2.46 MB)

    hipMemsetAsync(ws, 0, 81984, stream);   // hist + cnt + rank (contiguous)

    k_scan      <<<2048, 256, 0, stream>>>(in4, cnt, ckey, cidx);
    k_check     <<<1, 1, 0, stream>>>(cnt);
    k_hist_fb   <<<1024, 256, 0, stream>>>(in, cnt, hist);
    k_pivot_fb  <<<1, 256, 0, stream>>>(hist, cnt);
    k_compact_fb<<<1024, 256, 0, stream>>>(in, cnt, ckey, cidx);
    k_rank      <<<dim3(64, 16), 256, 0, stream>>>(ckey, cidx, cnt, rank);
    k_scatter   <<<64, 256, 0, stream>>>(ckey, cidx, cnt, rank, skey, sidx);
    k_decode    <<<16, 256, 0, stream>>>(in, skey, sidx, cand, keepg);
    k_mask      <<<dim3(16, 4096), 256, 0, stream>>>(cand, mask, dp);
    k_nms       <<<1, 64, 0, stream>>>(mask, dp, keepg, cnt);
    k_final     <<<1, 256, 0, stream>>>(cand, keepg, cnt, outp);
}

// Round 14
// 167.708 us; speedup vs baseline: 1.1272x; 1.1272x over previous
//
#include <hip/hip_runtime.h>
#include <stdint.h>

typedef unsigned int u32;
typedef unsigned long long u64;

#define N_BOXES 6291456   // 128*128*128*3
#define N_FLOAT4 7864320  // N_BOXES*5/4  = 2048*256*15 exactly
#define KCAND 4096
#define TOPK 300
#define CAP 16384         // compact capacity; ~8.5K expected at s>=3.0 for this data
#define SCORE_TH -3.0f
#define NMS_TH 0.05f
#define FIXED_TH 3.0f     // conservative compact threshold (bin 0xC04)

#define GLD_LDS16(srcp, dstp) \
    __builtin_amdgcn_global_load_lds( \
        (const __attribute__((address_space(1))) u32*)(srcp), \
        (__attribute__((address_space(3))) u32*)(dstp), 16, 0, 0)

__device__ __forceinline__ u32 sortable(float f) {
    u32 b = __float_as_uint(f);
    return (b & 0x80000000u) ? ~b : (b | 0x80000000u);
}

// Extract the (at most one) score in float4 #g: element index 4g+k with
// (4g+k) % 5 == 0. Returns false iff (4g)%5 == 1 (no score in this quad).
__device__ __forceinline__ bool quad_score(const float4& v, u32 g, float& s, u32& bidx) {
    u32 r = (4u * g) % 5u;
    if (r == 1u) return false;
    u32 k = (r == 0u) ? 0u : (5u - r);          // 0,3,2,1 for r=0,2,3,4
    s = (k == 0u) ? v.x : ((k == 1u) ? v.y : ((k == 2u) ? v.z : v.w));
    bidx = (4u * g + k) / 5u;
    return true;
}

// ---- Pass 1: compact all scores >= FIXED_TH (hot loop = loads+VALU only) ----
__global__ __launch_bounds__(256) void k_scan(const float4* __restrict__ in4,
                                              u32* __restrict__ cnt,
                                              u32* __restrict__ ckey, u32* __restrict__ cidx) {
    u32 base = blockIdx.x * 256u + threadIdx.x;
    u32 hits = 0;
#pragma unroll
    for (int k = 0; k < 15; ++k) {
        u32 g = base + (u32)k * 524288u;
        float4 v = in4[g];
        float s; u32 bidx;
        if (quad_score(v, g, s, bidx) && s >= FIXED_TH) hits |= 1u << k;
    }
    // rare path: re-read hit quads (L1/L2-hot), compact exactly once each
    while (hits) {
        int k = __builtin_ctz(hits);
        hits &= hits - 1;
        u32 g = base + (u32)k * 524288u;
        float4 v = in4[g];
        float s; u32 bidx;
        if (quad_score(v, g, s, bidx)) {
            u32 pos = atomicAdd(&cnt[0], 1u);
            if (pos < (u32)CAP) { ckey[pos] = sortable(s); cidx[pos] = bidx; }
        }
    }
}

// ---- Pass 2: validate the conservative compact; arm fallback if needed ----
__global__ void k_check(u32* __restrict__ cnt) {
    u32 m = cnt[0];
    u32 ok = (m >= (u32)KCAND && m <= (u32)CAP) ? 1u : 0u;
    cnt[2] = ok;
    if (!ok) cnt[0] = 0;   // fallback refills from scratch with exact B*
}

// ---- Fallback chain (guarded; no-ops when cnt[2]==1, the common case) ----
__global__ void k_hist_fb(const float* __restrict__ in, const u32* __restrict__ cnt,
                          u32* __restrict__ hist) {
    if (cnt[2] == 1u) return;
    __shared__ u32 lh[4096];
    for (int k = threadIdx.x; k < 4096; k += blockDim.x) lh[k] = 0;
    __syncthreads();
    int stride = gridDim.x * blockDim.x;
    for (int i = blockIdx.x * blockDim.x + threadIdx.x; i < N_BOXES; i += stride) {
        float f = in[(size_t)i * 5];
        u32 key = (f > SCORE_TH) ? sortable(f) : 0u;
        atomicAdd(&lh[key >> 20], 1u);
    }
    __syncthreads();
    for (int k = threadIdx.x; k < 4096; k += blockDim.x)
        if (lh[k]) atomicAdd(&hist[k], lh[k]);
}

__global__ void k_pivot_fb(const u32* __restrict__ hist, u32* __restrict__ cnt) {
    if (cnt[2] == 1u) return;
    __shared__ u32 part[256];
    int t = threadIdx.x;
    u32 s = 0;
    for (int k = 0; k < 16; ++k) s += hist[t * 16 + k];
    part[t] = s;
    __syncthreads();
    if (t == 0) {
        u32 acc = 0; int chunk = -1;
        for (int c = 255; c >= 0; --c) {
            if (acc + part[c] >= (u32)KCAND) { chunk = c; break; }
            acc += part[c];
        }
        u32 bstar = 0;
        if (chunk >= 0) {
            for (int b = chunk * 16 + 15; b >= chunk * 16; --b) {
                acc += hist[b];
                if (acc >= (u32)KCAND) { bstar = (u32)b; break; }
            }
        }
        cnt[1] = bstar;
    }
}

__global__ void k_compact_fb(const float* __restrict__ in, u32* __restrict__ cnt,
                             u32* __restrict__ ckey, u32* __restrict__ cidx) {
    if (cnt[2] == 1u) return;
    u32 bstar = cnt[1];
    int stride = gridDim.x * blockDim.x;
    for (int i = blockIdx.x * blockDim.x + threadIdx.x; i < N_BOXES; i += stride) {
        float f = in[(size_t)i * 5];
        u32 key = (f > SCORE_TH) ? sortable(f) : 0u;
        if ((key >> 20) >= bstar) {
            u32 pos = atomicAdd(&cnt[0], 1u);
            if (pos < (u32)CAP) { ckey[pos] = key; cidx[pos] = (u32)i; }
        }
    }
}

// ---- Pass 4: exact rank by (key desc, idx asc); grid (CAP/256, CAP/1024) ----
__global__ void k_rank(const u32* __restrict__ ckey, const u32* __restrict__ cidx,
                       const u32* __restrict__ cnt, u32* __restrict__ rank) {
    int M = (int)min(cnt[0], (u32)CAP);
    int e = blockIdx.x * 256 + threadIdx.x;
    bool act = (e < M);
    u32 mykey = 0, myidx = 0;
    if (act) { mykey = ckey[e]; myidx = cidx[e]; }
    int j0 = blockIdx.y * 1024;
    int j1 = min(j0 + 1024, M);
    __shared__ u32 sk[256], si[256];
    u32 r = 0;
    for (int base = j0; base < j1; base += 256) {
        __syncthreads();
        int jj = base + threadIdx.x;
        if (jj < j1) { sk[threadIdx.x] = ckey[jj]; si[threadIdx.x] = cidx[jj]; }
        __syncthreads();
        int lim = min(256, j1 - base);
        if (act) {
            for (int q = 0; q < lim; ++q) {
                u32 kq = sk[q];
                r += (u32)((kq > mykey) || (kq == mykey && si[q] < myidx));
            }
        }
    }
    if (act && r) atomicAdd(&rank[e], r);
}

__global__ void k_scatter(const u32* __restrict__ ckey, const u32* __restrict__ cidx,
                          const u32* __restrict__ cnt, const u32* __restrict__ rank,
                          u32* __restrict__ skey, u32* __restrict__ sidx) {
    int M = (int)min(cnt[0], (u32)CAP);
    int e = blockIdx.x * 256 + threadIdx.x;
    if (e < M) {
        u32 r = rank[e];
        if (r < (u32)KCAND) { skey[r] = ckey[e]; sidx[r] = cidx[e]; }
    }
}

// ---- Pass 5: decode the 4096 selected boxes; build validity bitmask ----
__global__ void k_decode(const float* __restrict__ in, const u32* __restrict__ skey,
                         const u32* __restrict__ sidx, float* __restrict__ cand,
                         u64* __restrict__ keepg) {
#pragma clang fp contract(off)
    int r = blockIdx.x * 256 + threadIdx.x;   // grid 16 x 256 = 4096 exactly
    u32 key = skey[r];
    u32 idx = sidx[r];
    u32 a = idx % 3u;
    u32 rem = idx / 3u;
    u32 w = rem & 127u; rem >>= 7;
    u32 h = rem & 127u;
    u32 z = rem >> 7;
    float anch = (a == 0u) ? 10.0f : ((a == 1u) ? 30.0f : 60.0f);
    const float* p = in + (size_t)idx * 5;
    float s  = p[0];
    float zc = (1.5f + 4.0f * (float)z) + p[1] * anch;
    float yc = (1.5f + 4.0f * (float)h) + p[2] * anch;
    float xc = (1.5f + 4.0f * (float)w) + p[3] * anch;
    float d  = expf(p[4]) * anch;
    float* o = cand + (size_t)r * 5;
    o[0] = s; o[1] = zc; o[2] = yc; o[3] = xc; o[4] = d;
    u64 bal = __ballot(key != 0u);    // valid = score > THRESH (key==0 means filtered)
    if ((threadIdx.x & 63) == 0) keepg[r >> 6] = bal;
}

// ---- Pass 6: suppression bitmask; 16 i-rows per block (j-box in regs) ----
__global__ void k_mask(const float* __restrict__ cand, u64* __restrict__ mask) {
#pragma clang fp contract(off)
    int wv = blockIdx.x * 4 + (threadIdx.x >> 6);
    int j = wv * 64 + (threadIdx.x & 63);
    const float* bj = cand + (size_t)j * 5;
    float zj = bj[1], yj = bj[2], xj = bj[3], dj = bj[4];
    float rj = dj * 0.5f;
    float vj = (dj * dj) * dj;
    int i0 = blockIdx.y * 16;
#pragma unroll
    for (int ii = 0; ii < 16; ++ii) {
        int i = i0 + ii;
        const float* bi = cand + (size_t)i * 5;
        float zi = bi[1], yi = bi[2], xi = bi[3], di = bi[4];
        float ri = di * 0.5f;
        float ov0 = fmaxf(0.0f, fminf(zi + ri, zj + rj) - fmaxf(zi - ri, zj - rj));
        float ov1 = fmaxf(0.0f, fminf(yi + ri, yj + rj) - fmaxf(yi - ri, yj - rj));
        float ov2 = fmaxf(0.0f, fminf(xi + ri, xj + rj) - fmaxf(xi - ri, xj - rj));
        float inter = (ov0 * ov1) * ov2;
        float vi = (di * di) * di;
        float iou = inter / ((vi + vj) - inter);
        bool bit = (j > i) && (iou >= NMS_TH);
        u64 bal = __ballot(bit);
        if ((threadIdx.x & 63) == 0) mask[(size_t)i * 64 + wv] = bal;
    }
}

// ---- Pass 7: greedy NMS (8-wave tile streaming + early exit) fused with
// the final top-300 output. Same proven resolve/apply math as R12.
__global__ __launch_bounds__(512) void k_nms(const u64* __restrict__ mask,
                                             const u64* __restrict__ keepg,
                                             const float* __restrict__ cand,
                                             float* __restrict__ outp) {
    __shared__ u64 tile[2][4096];   // 2 x 32 KB, linear [row][word]
    __shared__ int sstop;
    __shared__ u64 kw[64];
    __shared__ u32 wp[65];
    int lane = threadIdx.x & 63;
    int wave = threadIdx.x >> 6;    // 0..7
    u64 K = (wave == 0) ? keepg[lane] : 0ull;
    int keptTotal = 0;
    if (threadIdx.x == 0) sstop = 64;

    // prologue: stage chunk 0 into tile[0] (each wave a 4 KB slice)
    {
        const char* src = (const char*)mask + wave * 4096 + lane * 16;
        char* dst = (char*)&tile[0][0] + wave * 4096;
#pragma unroll
        for (int i = 0; i < 4; ++i)
            GLD_LDS16(src + i * 1024, dst + i * 1024);
    }

    int resolved = 63;
    for (int c = 0; c < 64; ++c) {
        asm volatile("s_waitcnt vmcnt(0)" ::: "memory");   // own slice landed
        __syncthreads();                                    // all slices landed; orders sstop
        if (c > sstop) { resolved = sstop; break; }
        const u64* tl = &tile[c & 1][0];
        // issue next chunk's slice loads (flight hides under wave-0 compute)
        if (c + 1 < 64) {
            const char* src = (const char*)(mask + (size_t)(c + 1) * 4096) + wave * 4096 + lane * 16;
            char* dst = (char*)&tile[(c + 1) & 1][0] + wave * 4096;
#pragma unroll
            for (int i = 0; i < 4; ++i)
                GLD_LDS16(src + i * 1024, dst + i * 1024);
        }
        if (wave == 0) {
            u64 diag = tl[lane * 64 + c];
            u32 dlo = (u32)diag, dhi = (u32)(diag >> 32);
            u32 kwlo = (u32)__builtin_amdgcn_readlane((int)(u32)K, c);
            u32 kwhi = (u32)__builtin_amdgcn_readlane((int)(u32)(K >> 32), c);
            u64 remaining = ((u64)kwhi << 32) | kwlo;
            u64 kept = 0;
            while (remaining) {
                int b = __builtin_ctzll(remaining);
                kept |= 1ull << b;
                u32 rlo = (u32)__builtin_amdgcn_readlane((int)dlo, b);
                u32 rhi = (u32)__builtin_amdgcn_readlane((int)dhi, b);
                u64 rb = ((u64)rhi << 32) | rlo;   // bits > b only
                remaining &= ~(rb | (1ull << b));
            }
            u64 s0 = 0, s1 = 0, s2 = 0, s3 = 0;
#pragma unroll
            for (int b = 0; b < 64; b += 4) {
                u64 m0 = ((kept >> (b + 0)) & 1ull) ? ~0ull : 0ull;
                u64 m1 = ((kept >> (b + 1)) & 1ull) ? ~0ull : 0ull;
                u64 m2 = ((kept >> (b + 2)) & 1ull) ? ~0ull : 0ull;
                u64 m3 = ((kept >> (b + 3)) & 1ull) ? ~0ull : 0ull;
                s0 |= tl[(b + 0) * 64 + lane] & m0;
                s1 |= tl[(b + 1) * 64 + lane] & m1;
                s2 |= tl[(b + 2) * 64 + lane] & m2;
                s3 |= tl[(b + 3) * 64 + lane] & m3;
            }
            K &= ~((s0 | s1) | (s2 | s3));
            keptTotal += (int)__popcll(kept);
            if (lane == 0 && keptTotal >= TOPK && sstop == 64) sstop = c;
        }
    }
    asm volatile("s_waitcnt vmcnt(0)" ::: "memory");   // drain in-flight LDS-DMA
    __syncthreads();

    // ---- fused final: top-300 = kept positions asc, then non-kept asc ----
    // Words beyond 'resolved' can only map to slots >= TOPK (early exit fired
    // because >= TOPK boxes were already kept), so zeroing them is exact.
    if (wave == 0) kw[lane] = (lane <= resolved) ? K : 0ull;
    __syncthreads();
    if (threadIdx.x == 0) {
        u32 acc = 0;
        for (int w2 = 0; w2 < 64; ++w2) { wp[w2] = acc; acc += (u32)__popcll(kw[w2]); }
        wp[64] = acc;
    }
    __syncthreads();
    u32 nk = wp[64];
    int rmax = (resolved + 1) * 64;
    for (int r = threadIdx.x; r < rmax; r += 512) {
        u64 word = kw[r >> 6];
        int b = r & 63;
        bool kept = (word >> b) & 1ull;
        u64 lowmask = b ? (~0ull >> (64 - b)) : 0ull;
        u32 before = wp[r >> 6] + (u32)__popcll(word & lowmask);
        u32 slot = kept ? before : (nk + (u32)r - before);
        if (slot < (u32)TOPK) {
            const float* src = cand + (size_t)r * 5;
            float* dst = outp + (size_t)slot * 5;
            dst[0] = src[0]; dst[1] = src[1]; dst[2] = src[2];
            dst[3] = src[3]; dst[4] = src[4];
        }
    }
}

extern "C" void kernel_launch(void* const* d_in, const int* in_sizes, int n_in,
                              void* d_out, int out_size, void* d_ws, size_t ws_size,
                              hipStream_t stream) {
    const float* in = (const float*)d_in[0];
    const float4* in4 = (const float4*)d_in[0];
    float* outp = (float*)d_out;
    char* ws = (char*)d_ws;

    // workspace layout (bytes), CAP = 16384
    u32* hist = (u32*)(ws + 0);            // 16384
    u32* cnt  = (u32*)(ws + 16384);        // 64
    u32* rank = (u32*)(ws + 16448);        // 65536
    u32* ckey = (u32*)(ws + 81984);        // 65536
    u32* cidx = (u32*)(ws + 147520);       // 65536
    u32* skey = (u32*)(ws + 213056);       // 16384
    u32* sidx = (u32*)(ws + 229440);       // 16384
    float* cand = (float*)(ws + 245824);   // 81920
    u64* keepg  = (u64*)(ws + 327744);     // 512
    u64* mask   = (u64*)(ws + 328256);     // 2097152   (total ~2.43 MB)

    hipMemsetAsync(ws, 0, 81984, stream);   // hist + cnt + rank (contiguous)

    k_scan      <<<2048, 256, 0, stream>>>(in4, cnt, ckey, cidx);
    k_check     <<<1, 1, 0, stream>>>(cnt);
    k_hist_fb   <<<1024, 256, 0, stream>>>(in, cnt, hist);
    k_pivot_fb  <<<1, 256, 0, stream>>>(hist, cnt);
    k_compact_fb<<<1024, 256, 0, stream>>>(in, cnt, ckey, cidx);
    k_rank      <<<dim3(64, 16), 256, 0, stream>>>(ckey, cidx, cnt, rank);
    k_scatter   <<<64, 256, 0, stream>>>(ckey, cidx, cnt, rank, skey, sidx);
    k_decode    <<<16, 256, 0, stream>>>(in, skey, sidx, cand, keepg);
    k_mask      <<<dim3(16, 256), 256, 0, stream>>>(cand, mask);
    k_nms       <<<1, 512, 0, stream>>>(mask, keepg, cand, outp);
}